// Round 21
// baseline (790.352 us; speedup 1.0000x reference)
//
#include <hip/hip_runtime.h>
#include <hip/hip_bf16.h>

typedef short short8 __attribute__((ext_vector_type(8)));
typedef float floatx4 __attribute__((ext_vector_type(4)));
typedef __hip_bfloat16 bf16;

#define HID 256
#define NL  4
#define AS1 __attribute__((address_space(1)))
#define AS3 __attribute__((address_space(3)))

__device__ __forceinline__ float b2f(bf16 v) { return __bfloat162float(v); }
__device__ __forceinline__ bf16 f2b(float v) { return __float2bfloat16(v); }
__device__ __forceinline__ float us2f(unsigned short u) {
    unsigned int x = ((unsigned int)u) << 16;
    return __uint_as_float(x);
}
__device__ __forceinline__ unsigned short f2us(float v) {
    bf16 t = __float2bfloat16(v);
    return *reinterpret_cast<unsigned short*>(&t);
}

// ---------------- fused zero-init ----------------
__global__ void zero_ws_kernel(int* __restrict__ a, int* __restrict__ b, int n,
                               float* __restrict__ p, int np) {
    int i = blockIdx.x * 256 + threadIdx.x;
    if (i < n) { a[i] = 0; b[i] = 0; }
    if (i < np) p[i] = 0.f;
}

// ---------------- embeddings (float32 inputs); h lives ONLY as bf16 ----------------
__global__ void node_embed_kernel(const int* __restrict__ x,
                                  const float* __restrict__ e0, const float* __restrict__ e1,
                                  const float* __restrict__ e2,
                                  bf16* __restrict__ hbf) {
    int n = blockIdx.x, c = threadIdx.x;
    int i0 = x[n * 3], i1 = x[n * 3 + 1], i2 = x[n * 3 + 2];
    float v = e0[i0 * HID + c] + e1[i1 * HID + c] + e2[i2 * HID + c];
    hbf[(size_t)n * HID + c] = f2b(v);
}

__global__ void ecombo_embed_kernel(const float* __restrict__ e0, const float* __restrict__ e1,
                                    float* __restrict__ ec) {
    int i = blockIdx.x, c = threadIdx.x;
    ec[i * HID + c] = e0[(i >> 2) * HID + c] + e1[(i & 3) * HID + c];
}

// merged: per-edge combo id + dst histogram
__global__ void edge_prep_kernel(const int* __restrict__ ea, const int* __restrict__ dst,
                                 int E, int* __restrict__ ecid, int* __restrict__ counts) {
    int e = blockIdx.x * 256 + threadIdx.x;
    if (e < E) {
        ecid[e] = ea[e * 2] * 4 + ea[e * 2 + 1];
        atomicAdd(&counts[dst[e]], 1);
    }
}

// ALL layers at once
__global__ void combo_proj_kernel(const float* __restrict__ ec, const float* __restrict__ We,
                                  const float* __restrict__ be, float* __restrict__ ecp4) {
    __shared__ float row[HID];
    int l = blockIdx.x >> 5, i = blockIdx.x & 31, c = threadIdx.x;
    row[c] = ec[i * HID + c];
    __syncthreads();
    const float* We_l = We + (size_t)l * 65536;
    float a = be[l * 256 + c];
    for (int k = 0; k < HID; ++k) a += row[k] * We_l[k * HID + c];
    ecp4[(size_t)l * 32 * HID + i * HID + c] = a;
}

// ---------------- CSR scan ----------------
__global__ void scan_local_kernel(const int* __restrict__ counts, int N,
                                  int* __restrict__ incl, int* __restrict__ bsum) {
    __shared__ int sd[256];
    int i = threadIdx.x;
    int idx = blockIdx.x * 256 + i;
    sd[i] = (idx < N) ? counts[idx] : 0;
    __syncthreads();
    for (int off = 1; off < 256; off <<= 1) {
        int t = (i >= off) ? sd[i - off] : 0;
        __syncthreads();
        sd[i] += t;
        __syncthreads();
    }
    if (idx < N) incl[idx] = sd[i];
    if (i == 255) bsum[blockIdx.x] = sd[255];
}

__global__ void scan_block_kernel(const int* __restrict__ bsum, int nb, int* __restrict__ boff) {
    __shared__ int sd[256];
    int i = threadIdx.x;
    sd[i] = (i < nb) ? bsum[i] : 0;
    __syncthreads();
    for (int off = 1; off < 256; off <<= 1) {
        int t = (i >= off) ? sd[i - off] : 0;
        __syncthreads();
        sd[i] += t;
        __syncthreads();
    }
    if (i < nb) boff[i] = (i == 0) ? 0 : sd[i - 1];
}

__global__ void scan_add_kernel(const int* __restrict__ incl, const int* __restrict__ boff,
                                int N, int* __restrict__ indptr) {
    int idx = blockIdx.x * 256 + threadIdx.x;
    if (idx < N) indptr[idx + 1] = incl[idx] + boff[blockIdx.x];
    if (idx == 0) indptr[0] = 0;
}

__global__ void fill_sorted_kernel(const int* __restrict__ dst, const int* __restrict__ srcv,
                                   const int* __restrict__ ecid, const int* __restrict__ indptr,
                                   int E, int* __restrict__ fill, int2* __restrict__ sorted2) {
    int e = blockIdx.x * 256 + threadIdx.x;
    if (e < E) {
        int d = dst[e];
        int pos = indptr[d] + atomicAdd(&fill[d], 1);
        sorted2[pos] = make_int2(srcv[e], ecid[e]);
    }
}

// ---------------- weight packing, KV-interleaved ----------------
__global__ void pack_wcat_kernel(const float* __restrict__ Wq, const float* __restrict__ Wk,
                                 const float* __restrict__ Wv, const float* __restrict__ Ws,
                                 bf16* __restrict__ wcatT) {
    int idx = blockIdx.x * 256 + threadIdx.x;
    int l = idx >> 18;
    int rem = idx & 262143;
    int j = rem >> 8;
    int k = rem & 255;
    const float* W;
    int jj;
    if (j < 256)      { W = Wq; jj = j; }
    else if (j < 512) { W = Ws; jj = j - 256; }
    else {
        int g = (j - 512) >> 3, r = (j - 512) & 7;
        if (r < 4) { W = Wk; jj = 4 * g + r; }
        else       { W = Wv; jj = 4 * g + r - 4; }
    }
    wcatT[idx] = f2b(W[l * 65536 + k * 256 + jj]);
}

__global__ void pack_bias_kernel(const float* __restrict__ bq, const float* __restrict__ bk,
                                 const float* __restrict__ bv, const float* __restrict__ bs,
                                 float* __restrict__ bcat) {
    int idx = blockIdx.x * 256 + threadIdx.x;
    if (idx < 4096) {
        int l = idx >> 10, j = idx & 1023;
        const float* B;
        int jj;
        if (j < 256)      { B = bq; jj = j; }
        else if (j < 512) { B = bs; jj = j - 256; }
        else {
            int g = (j - 512) >> 3, r = (j - 512) & 7;
            if (r < 4) { B = bk; jj = 4 * g + r; }
            else       { B = bv; jj = 4 * g + r - 4; }
        }
        bcat[idx] = B[l * 256 + jj];
    }
}

// ---------------- MFMA GEMM: async global_load_lds staging, XOR-swizzled LDS ----------------
__global__ __launch_bounds__(512) void gemm_bt_kernel(
    const bf16* __restrict__ A, const bf16* __restrict__ BT,
    const float* __restrict__ bias, bf16* __restrict__ C, int M, int Nout) {
    constexpr int BM = 128, BN = 256, BK = 64, CSTR = 136;
    __shared__ __align__(16) bf16 smem[BM * 64 + BN * 64];   // 48 KB
    bf16* sA = smem;
    bf16* sB = smem + BM * 64;
    const int m0 = blockIdx.x * BM;
    const int n0 = blockIdx.y * BN;
    const int tid = threadIdx.x;
    const int lane = tid & 63;
    const int wave = tid >> 6;
    const int wm = (wave >> 2) * 64;
    const int wn = (wave & 3) * 64;
    const int fr = lane & 15;
    const int quad = lane >> 4;
    const int sub = lane >> 3;
    const int slot = lane & 7;
    const int jsw = slot ^ sub;
    floatx4 acc[4][4] = {};
    for (int kc = 0; kc < 256; kc += BK) {
#pragma unroll
        for (int p = 0; p < 2; ++p) {
            const int brow = (wave * 2 + p) * 8;
            const int gm = min(m0 + brow + sub, M - 1);
            __builtin_amdgcn_global_load_lds(
                (const AS1 void*)(A + (size_t)gm * 256 + kc + jsw * 8),
                (AS3 void*)(sA + brow * 64), 16, 0, 0);
        }
#pragma unroll
        for (int p = 0; p < 4; ++p) {
            const int brow = (wave * 4 + p) * 8;
            __builtin_amdgcn_global_load_lds(
                (const AS1 void*)(BT + (size_t)(n0 + brow + sub) * 256 + kc + jsw * 8),
                (AS3 void*)(sB + brow * 64), 16, 0, 0);
        }
        __syncthreads();
#pragma unroll
        for (int ks = 0; ks < BK; ks += 32) {
            const int ch = (ks >> 3) + quad;
            const int phys = (ch ^ (fr & 7)) << 3;
            short8 af[4], bfm[4];
#pragma unroll
            for (int i = 0; i < 4; ++i) {
                af[i]  = *reinterpret_cast<const short8*>(&sA[(wm + i * 16 + fr) * 64 + phys]);
                bfm[i] = *reinterpret_cast<const short8*>(&sB[(wn + i * 16 + fr) * 64 + phys]);
            }
#pragma unroll
            for (int mi = 0; mi < 4; ++mi)
#pragma unroll
                for (int ni = 0; ni < 4; ++ni)
                    acc[mi][ni] = __builtin_amdgcn_mfma_f32_16x16x32_bf16(af[mi], bfm[ni], acc[mi][ni], 0, 0, 0);
        }
        __syncthreads();
    }
    float bias4[4];
#pragma unroll
    for (int ni = 0; ni < 4; ++ni) bias4[ni] = bias[n0 + wn + ni * 16 + fr];
    bf16* sC = smem;
    const int myhalf = wn >> 7;
#pragma unroll
    for (int half = 0; half < 2; ++half) {
        if (myhalf == half) {
            const int wnl = wn & 127;
#pragma unroll
            for (int mi = 0; mi < 4; ++mi)
#pragma unroll
                for (int ni = 0; ni < 4; ++ni)
#pragma unroll
                    for (int r = 0; r < 4; ++r)
                        sC[(wm + mi * 16 + quad * 4 + r) * CSTR + wnl + ni * 16 + fr] =
                            f2b(acc[mi][ni][r] + bias4[ni]);
        }
        __syncthreads();
#pragma unroll
        for (int p = 0; p < 4; ++p) {
            int ci = tid + p * 512;
            int row = ci >> 4;
            int c8 = (ci & 15) << 3;
            if (m0 + row < M)
                *reinterpret_cast<uint4*>(C + (size_t)(m0 + row) * Nout + n0 + half * 128 + c8) =
                    *reinterpret_cast<const uint4*>(&sC[row * CSTR + c8]);
        }
        __syncthreads();
    }
}

// ---------------- fused attention: wave-per-node; ALL epilogue operands hoisted pre-loop ----------------
__global__ __launch_bounds__(256) void attn_node_kernel(
    const bf16* __restrict__ qkvs,     // [N,1024] q | skip | kv-interleaved
    const float* __restrict__ ecp,     // [32,256] this layer
    const int* __restrict__ indptr, const int2* __restrict__ sorted2,
    const float* __restrict__ Wbeta_l, const float* __restrict__ lng, const float* __restrict__ lnb,
    bf16* __restrict__ hbf, int N) {
    const int tid = threadIdx.x;
    const int wv = tid >> 6;
    const int lane = tid & 63;
    const int n = blockIdx.x * 4 + wv;
    if (n >= N) return;
    const int c0 = lane * 4;
    const ushort4 qu = *reinterpret_cast<const ushort4*>(qkvs + (size_t)n * 1024 + c0);
    // hoist epilogue operands: latency hidden under the edge loop
    const ushort4 ru = *reinterpret_cast<const ushort4*>(qkvs + (size_t)n * 1024 + 256 + c0);
    const float4 w1 = *reinterpret_cast<const float4*>(Wbeta_l + c0);
    const float4 w2 = *reinterpret_cast<const float4*>(Wbeta_l + 256 + c0);
    const float4 w3 = *reinterpret_cast<const float4*>(Wbeta_l + 512 + c0);
    const float4 gg = *reinterpret_cast<const float4*>(lng + c0);
    const float4 bb = *reinterpret_cast<const float4*>(lnb + c0);
    const ushort4 hb_in = *reinterpret_cast<ushort4*>(hbf + (size_t)n * HID + c0);
    const float q0 = us2f(qu.x), q1 = us2f(qu.y), q2 = us2f(qu.z), q3 = us2f(qu.w);
    float a0 = 0.f, a1 = 0.f, a2 = 0.f, a3 = 0.f, wsum = 0.f;
    const int e0 = indptr[n], e1 = indptr[n + 1];
    float4 ep_c;
    uint4 kv_c;
    if (e0 < e1) {
        const int2 sc = sorted2[e0];
        ep_c = *reinterpret_cast<const float4*>(ecp + sc.y * HID + c0);
        kv_c = *reinterpret_cast<const uint4*>(qkvs + (size_t)sc.x * 1024 + 512 + lane * 8);
    }
    for (int ee = e0; ee < e1; ++ee) {
        const float4 ep = ep_c;
        const uint4 kv = kv_c;
        if (ee + 1 < e1) {
            const int2 sc = sorted2[ee + 1];
            ep_c = *reinterpret_cast<const float4*>(ecp + sc.y * HID + c0);
            kv_c = *reinterpret_cast<const uint4*>(qkvs + (size_t)sc.x * 1024 + 512 + lane * 8);
        }
        const float k0 = us2f((unsigned short)(kv.x & 0xffff)), k1 = us2f((unsigned short)(kv.x >> 16));
        const float k2 = us2f((unsigned short)(kv.y & 0xffff)), k3 = us2f((unsigned short)(kv.y >> 16));
        const float v0 = us2f((unsigned short)(kv.z & 0xffff)), v1 = us2f((unsigned short)(kv.z >> 16));
        const float v2 = us2f((unsigned short)(kv.w & 0xffff)), v3 = us2f((unsigned short)(kv.w >> 16));
        float t = q0 * (k0 + ep.x) + q1 * (k1 + ep.y) + q2 * (k2 + ep.z) + q3 * (k3 + ep.w);
        t += __shfl_xor(t, 1); t += __shfl_xor(t, 2); t += __shfl_xor(t, 4); t += __shfl_xor(t, 8);
        const float w = __expf(t * 0.125f);
        a0 += w * (v0 + ep.x);
        a1 += w * (v1 + ep.y);
        a2 += w * (v2 + ep.z);
        a3 += w * (v3 + ep.w);
        wsum += w;
    }
    const float inv = (wsum > 0.f) ? 1.f / wsum : 0.f;
    const float o0 = a0 * inv, o1 = a1 * inv, o2 = a2 * inv, o3 = a3 * inv;
    const float r0 = us2f(ru.x), r1 = us2f(ru.y), r2 = us2f(ru.z), r3 = us2f(ru.w);
    float tb = o0 * w1.x + o1 * w1.y + o2 * w1.z + o3 * w1.w
             + r0 * w2.x + r1 * w2.y + r2 * w2.z + r3 * w2.w
             + (o0 - r0) * w3.x + (o1 - r1) * w3.y + (o2 - r2) * w3.z + (o3 - r3) * w3.w;
#pragma unroll
    for (int off = 32; off > 0; off >>= 1) tb += __shfl_xor(tb, off);
    const float beta = 1.f / (1.f + __expf(-tb));
    float g0 = fmaxf(beta * r0 + (1.f - beta) * o0, 0.f);
    float g1 = fmaxf(beta * r1 + (1.f - beta) * o1, 0.f);
    float g2 = fmaxf(beta * r2 + (1.f - beta) * o2, 0.f);
    float g3 = fmaxf(beta * r3 + (1.f - beta) * o3, 0.f);
    float s1 = g0 + g1 + g2 + g3;
    float s2 = g0 * g0 + g1 * g1 + g2 * g2 + g3 * g3;
#pragma unroll
    for (int off = 32; off > 0; off >>= 1) { s1 += __shfl_xor(s1, off); s2 += __shfl_xor(s2, off); }
    const float mu = s1 * (1.f / 256.f);
    const float var = s2 * (1.f / 256.f) - mu * mu;
    const float rish = rsqrtf(fmaxf(var, 0.f) + 1e-5f);
    ushort4 hb;
    hb.x = f2us(us2f(hb_in.x) + (g0 - mu) * rish * gg.x + bb.x);
    hb.y = f2us(us2f(hb_in.y) + (g1 - mu) * rish * gg.y + bb.y);
    hb.z = f2us(us2f(hb_in.z) + (g2 - mu) * rish * gg.z + bb.z);
    hb.w = f2us(us2f(hb_in.w) + (g3 - mu) * rish * gg.w + bb.w);
    *reinterpret_cast<ushort4*>(hbf + (size_t)n * HID + c0) = hb;
}

// ---------------- hierarchical pooling (reads bf16 h) ----------------
__global__ __launch_bounds__(256) void pool_kernel(const bf16* __restrict__ hbf,
                                                   const int* __restrict__ batch,
                                                   float* __restrict__ pooled, int N) {
    __shared__ int sb[64];
    const int c = threadIdx.x;
    const int n0 = blockIdx.x * 64;
    const int cnt = min(64, N - n0);
    if (c < 64 && c < cnt) sb[c] = batch[n0 + c];
    __syncthreads();
    float acc = 0.f;
    int gcur = sb[0];
    for (int i = 0; i < cnt; ++i) {
        const int g = sb[i];
        if (g != gcur) {
            atomicAdd(&pooled[(size_t)gcur * HID + c], acc);
            acc = 0.f;
            gcur = g;
        }
        acc += b2f(hbf[(size_t)(n0 + i) * HID + c]);
    }
    atomicAdd(&pooled[(size_t)gcur * HID + c], acc);
}

__global__ void pragma_kernel(const float* __restrict__ scalars,
                              const float* __restrict__ pw1, const float* __restrict__ pb1,
                              const float* __restrict__ pw2, const float* __restrict__ pb2,
                              float* __restrict__ pooled) {
    int g = blockIdx.x, c = threadIdx.x;
    __shared__ float s5[5];
    __shared__ float t1[256];
    if (c < 5) s5[c] = scalars[g * 5 + c];
    __syncthreads();
    float a = pb1[c];
    for (int k = 0; k < 5; ++k) a += s5[k] * pw1[k * 256 + c];
    t1[c] = fmaxf(a, 0.f);
    __syncthreads();
    float p = pb2[c];
    for (int j = 0; j < 256; ++j) p += t1[j] * pw2[j * 256 + c];
    pooled[g * 256 + c] += p;
}

__global__ void readout_kernel(const float* __restrict__ pooled,
                               const float* __restrict__ rw1, const float* __restrict__ rb1,
                               const float* __restrict__ rw2, const float* __restrict__ rb2,
                               const float* __restrict__ rw3, const float* __restrict__ rb3,
                               float* __restrict__ out) {
    int g = blockIdx.x, c = threadIdx.x;
    __shared__ float pl[256], z1[256], z2[128];
    pl[c] = pooled[g * 256 + c];
    __syncthreads();
    float z = rb1[c];
    for (int k = 0; k < 256; ++k) z += pl[k] * rw1[k * 256 + c];
    z1[c] = fmaxf(z, 0.f);
    __syncthreads();
    if (c < 128) {
        float v = rb2[c];
        for (int j = 0; j < 256; ++j) v += z1[j] * rw2[j * 128 + c];
        z2[c] = fmaxf(v, 0.f);
    }
    __syncthreads();
    if (c < 4) {
        float o = rb3[c];
        for (int j = 0; j < 128; ++j) o += z2[j] * rw3[j * 4 + c];
        out[g * 4 + c] = o;
    }
}

extern "C" void kernel_launch(void* const* d_in, const int* in_sizes, int n_in,
                              void* d_out, int out_size, void* d_ws, size_t ws_size,
                              hipStream_t stream) {
    const int* x          = (const int*)d_in[0];
    const int* edge_attr  = (const int*)d_in[1];
    const int* edge_index = (const int*)d_in[2];
    const int* batch      = (const int*)d_in[3];
    const float* scalars  = (const float*)d_in[4];
    const float* ne0 = (const float*)d_in[6];
    const float* ne1 = (const float*)d_in[7];
    const float* ne2 = (const float*)d_in[8];
    const float* ee0 = (const float*)d_in[9];
    const float* ee1 = (const float*)d_in[10];
    const float* Wq = (const float*)d_in[11];
    const float* bq = (const float*)d_in[12];
    const float* Wk = (const float*)d_in[13];
    const float* bk = (const float*)d_in[14];
    const float* Wv = (const float*)d_in[15];
    const float* bv = (const float*)d_in[16];
    const float* We = (const float*)d_in[17];
    const float* be = (const float*)d_in[18];
    const float* Wskip = (const float*)d_in[19];
    const float* bskip = (const float*)d_in[20];
    const float* Wbeta = (const float*)d_in[21];
    const float* ln_g = (const float*)d_in[22];
    const float* ln_b = (const float*)d_in[23];
    const float* pw1 = (const float*)d_in[24];
    const float* pb1 = (const float*)d_in[25];
    const float* pw2 = (const float*)d_in[26];
    const float* pb2 = (const float*)d_in[27];
    const float* rw1 = (const float*)d_in[28];
    const float* rb1 = (const float*)d_in[29];
    const float* rw2 = (const float*)d_in[30];
    const float* rb2 = (const float*)d_in[31];
    const float* rw3 = (const float*)d_in[32];
    const float* rb3 = (const float*)d_in[33];

    const int N = in_sizes[0] / 3;
    const int E = in_sizes[1] / 2;
    const int G = in_sizes[4] / 5;

    char* base = (char*)d_ws;
    size_t off = 0;
    auto carve = [&](size_t bytes) -> char* {
        char* p = base + off;
        off += (bytes + 255) & ~(size_t)255;
        return p;
    };
    bf16*  hbf    = (bf16*)carve((size_t)N * HID * 2);
    bf16*  qkvs   = (bf16*)carve((size_t)N * 1024 * 2);
    float* ec     = (float*)carve((size_t)32 * HID * 4);
    float* ecp4   = (float*)carve((size_t)NL * 32 * HID * 4);
    int*   ecid   = (int*)carve((size_t)E * 4);
    float* pooled = (float*)carve((size_t)G * HID * 4);
    bf16*  wcatT  = (bf16*)carve((size_t)NL * 1024 * 256 * 2);
    float* bcat   = (float*)carve((size_t)NL * 1024 * 4);
    int* counts   = (int*)carve((size_t)N * 4);
    int* fill     = (int*)carve((size_t)N * 4);
    int* incl     = (int*)carve((size_t)N * 4);
    int* bsum     = (int*)carve(4096);
    int* boff     = (int*)carve(4096);
    int* indptr   = (int*)carve((size_t)(N + 1) * 4);
    int2* sorted2 = (int2*)carve((size_t)E * 8);
    // total ~140 MB

    const int* srcv = edge_index;
    const int* dstv = edge_index + E;

    zero_ws_kernel<<<(N + 255) / 256, 256, 0, stream>>>(counts, fill, N, pooled, G * HID);
    node_embed_kernel<<<N, 256, 0, stream>>>(x, ne0, ne1, ne2, hbf);
    ecombo_embed_kernel<<<32, 256, 0, stream>>>(ee0, ee1, ec);
    edge_prep_kernel<<<(E + 255) / 256, 256, 0, stream>>>(edge_attr, dstv, E, ecid, counts);
    pack_wcat_kernel<<<4096, 256, 0, stream>>>(Wq, Wk, Wv, Wskip, wcatT);
    pack_bias_kernel<<<16, 256, 0, stream>>>(bq, bk, bv, bskip, bcat);
    combo_proj_kernel<<<NL * 32, 256, 0, stream>>>(ec, We, be, ecp4);

    int nsb = (N + 255) / 256;
    scan_local_kernel<<<nsb, 256, 0, stream>>>(counts, N, incl, bsum);
    scan_block_kernel<<<1, 256, 0, stream>>>(bsum, nsb, boff);
    scan_add_kernel<<<nsb, 256, 0, stream>>>(incl, boff, N, indptr);
    fill_sorted_kernel<<<(E + 255) / 256, 256, 0, stream>>>(dstv, srcv, ecid, indptr, E, fill, sorted2);

    for (int l = 0; l < NL; ++l) {
        dim3 g1((N + 127) / 128, 4);
        gemm_bt_kernel<<<g1, 512, 0, stream>>>(hbf, wcatT + (size_t)l * 1024 * 256,
                                               bcat + (size_t)l * 1024, qkvs, N, 1024);
        attn_node_kernel<<<(N + 3) / 4, 256, 0, stream>>>(qkvs, ecp4 + (size_t)l * 32 * HID,
                                                          indptr, sorted2,
                                                          Wbeta + (size_t)l * 768,
                                                          ln_g + (size_t)l * 256, ln_b + (size_t)l * 256,
                                                          hbf, N);
    }

    pool_kernel<<<(N + 63) / 64, 256, 0, stream>>>(hbf, batch, pooled, N);
    pragma_kernel<<<G, 256, 0, stream>>>(scalars, pw1, pb1, pw2, pb2, pooled);
    readout_kernel<<<G, 256, 0, stream>>>(pooled, rw1, rb1, rw2, rb2, rw3, rb3, (float*)d_out);
}

// Round 22
// 740.735 us; speedup vs baseline: 1.0670x; 1.0670x over previous
//
#include <hip/hip_runtime.h>
#include <hip/hip_bf16.h>

typedef short short8 __attribute__((ext_vector_type(8)));
typedef float floatx4 __attribute__((ext_vector_type(4)));
typedef __hip_bfloat16 bf16;

#define HID 256
#define NL  4
#define AS1 __attribute__((address_space(1)))
#define AS3 __attribute__((address_space(3)))

__device__ __forceinline__ float b2f(bf16 v) { return __bfloat162float(v); }
__device__ __forceinline__ bf16 f2b(float v) { return __float2bfloat16(v); }
__device__ __forceinline__ float us2f(unsigned short u) {
    unsigned int x = ((unsigned int)u) << 16;
    return __uint_as_float(x);
}
__device__ __forceinline__ unsigned short f2us(float v) {
    bf16 t = __float2bfloat16(v);
    return *reinterpret_cast<unsigned short*>(&t);
}

// ---------------- fused zero-init: counts, fill (N each) + pooled (G*HID) ----------------
__global__ void zero_ws_kernel(int* __restrict__ a, int* __restrict__ b, int n,
                               float* __restrict__ p, int np) {
    int i = blockIdx.x * 256 + threadIdx.x;
    if (i < n) { a[i] = 0; b[i] = 0; }
    if (i < np) p[i] = 0.f;
}

// ---------------- embeddings (float32 inputs); h lives ONLY as bf16 ----------------
__global__ void node_embed_kernel(const int* __restrict__ x,
                                  const float* __restrict__ e0, const float* __restrict__ e1,
                                  const float* __restrict__ e2,
                                  bf16* __restrict__ hbf) {
    int n = blockIdx.x, c = threadIdx.x;
    int i0 = x[n * 3], i1 = x[n * 3 + 1], i2 = x[n * 3 + 2];
    float v = e0[i0 * HID + c] + e1[i1 * HID + c] + e2[i2 * HID + c];
    hbf[(size_t)n * HID + c] = f2b(v);
}

__global__ void ecombo_embed_kernel(const float* __restrict__ e0, const float* __restrict__ e1,
                                    float* __restrict__ ec) {
    int i = blockIdx.x, c = threadIdx.x;
    ec[i * HID + c] = e0[(i >> 2) * HID + c] + e1[(i & 3) * HID + c];
}

// merged: per-edge combo id + dst histogram (one pass over edges)
__global__ void edge_prep_kernel(const int* __restrict__ ea, const int* __restrict__ dst,
                                 int E, int* __restrict__ ecid, int* __restrict__ counts) {
    int e = blockIdx.x * 256 + threadIdx.x;
    if (e < E) {
        ecid[e] = ea[e * 2] * 4 + ea[e * 2 + 1];
        atomicAdd(&counts[dst[e]], 1);
    }
}

// ALL layers at once: blockIdx.x = l*32 + i -> ecp4[l][i][c]
__global__ void combo_proj_kernel(const float* __restrict__ ec, const float* __restrict__ We,
                                  const float* __restrict__ be, float* __restrict__ ecp4) {
    __shared__ float row[HID];
    int l = blockIdx.x >> 5, i = blockIdx.x & 31, c = threadIdx.x;
    row[c] = ec[i * HID + c];
    __syncthreads();
    const float* We_l = We + (size_t)l * 65536;
    float a = be[l * 256 + c];
    for (int k = 0; k < HID; ++k) a += row[k] * We_l[k * HID + c];
    ecp4[(size_t)l * 32 * HID + i * HID + c] = a;
}

// ---------------- CSR scan ----------------
__global__ void scan_local_kernel(const int* __restrict__ counts, int N,
                                  int* __restrict__ incl, int* __restrict__ bsum) {
    __shared__ int sd[256];
    int i = threadIdx.x;
    int idx = blockIdx.x * 256 + i;
    sd[i] = (idx < N) ? counts[idx] : 0;
    __syncthreads();
    for (int off = 1; off < 256; off <<= 1) {
        int t = (i >= off) ? sd[i - off] : 0;
        __syncthreads();
        sd[i] += t;
        __syncthreads();
    }
    if (idx < N) incl[idx] = sd[i];
    if (i == 255) bsum[blockIdx.x] = sd[255];
}

__global__ void scan_block_kernel(const int* __restrict__ bsum, int nb, int* __restrict__ boff) {
    __shared__ int sd[256];
    int i = threadIdx.x;
    sd[i] = (i < nb) ? bsum[i] : 0;
    __syncthreads();
    for (int off = 1; off < 256; off <<= 1) {
        int t = (i >= off) ? sd[i - off] : 0;
        __syncthreads();
        sd[i] += t;
        __syncthreads();
    }
    if (i < nb) boff[i] = (i == 0) ? 0 : sd[i - 1];
}

__global__ void scan_add_kernel(const int* __restrict__ incl, const int* __restrict__ boff,
                                int N, int* __restrict__ indptr) {
    int idx = blockIdx.x * 256 + threadIdx.x;
    if (idx < N) indptr[idx + 1] = incl[idx] + boff[blockIdx.x];
    if (idx == 0) indptr[0] = 0;
}

__global__ void fill_sorted_kernel(const int* __restrict__ dst, const int* __restrict__ srcv,
                                   const int* __restrict__ ecid, const int* __restrict__ indptr,
                                   int E, int* __restrict__ fill, int2* __restrict__ sorted2) {
    int e = blockIdx.x * 256 + threadIdx.x;
    if (e < E) {
        int d = dst[e];
        int pos = indptr[d] + atomicAdd(&fill[d], 1);
        sorted2[pos] = make_int2(srcv[e], ecid[e]);
    }
}

// ---------------- weight packing with KV-INTERLEAVED output column order ----------------
__global__ void pack_wcat_kernel(const float* __restrict__ Wq, const float* __restrict__ Wk,
                                 const float* __restrict__ Wv, const float* __restrict__ Ws,
                                 bf16* __restrict__ wcatT) {
    int idx = blockIdx.x * 256 + threadIdx.x;      // < 4*1024*256
    int l = idx >> 18;
    int rem = idx & 262143;
    int j = rem >> 8;
    int k = rem & 255;
    const float* W;
    int jj;
    if (j < 256)      { W = Wq; jj = j; }
    else if (j < 512) { W = Ws; jj = j - 256; }
    else {
        int g = (j - 512) >> 3, r = (j - 512) & 7;
        if (r < 4) { W = Wk; jj = 4 * g + r; }
        else       { W = Wv; jj = 4 * g + r - 4; }
    }
    wcatT[idx] = f2b(W[l * 65536 + k * 256 + jj]);
}

__global__ void pack_bias_kernel(const float* __restrict__ bq, const float* __restrict__ bk,
                                 const float* __restrict__ bv, const float* __restrict__ bs,
                                 float* __restrict__ bcat) {
    int idx = blockIdx.x * 256 + threadIdx.x;      // < 4096
    if (idx < 4096) {
        int l = idx >> 10, j = idx & 1023;
        const float* B;
        int jj;
        if (j < 256)      { B = bq; jj = j; }
        else if (j < 512) { B = bs; jj = j - 256; }
        else {
            int g = (j - 512) >> 3, r = (j - 512) & 7;
            if (r < 4) { B = bk; jj = 4 * g + r; }
            else       { B = bv; jj = 4 * g + r - 4; }
        }
        bcat[idx] = B[l * 256 + jj];
    }
}

// ---------------- MFMA GEMM: async global_load_lds staging, XOR-swizzled unpadded LDS ----------------
__global__ __launch_bounds__(512) void gemm_bt_kernel(
    const bf16* __restrict__ A, const bf16* __restrict__ BT,
    const float* __restrict__ bias, bf16* __restrict__ C, int M, int Nout) {
    constexpr int BM = 128, BN = 256, BK = 64, CSTR = 136;
    __shared__ __align__(16) bf16 smem[BM * 64 + BN * 64];   // 48 KB
    bf16* sA = smem;
    bf16* sB = smem + BM * 64;
    const int m0 = blockIdx.x * BM;
    const int n0 = blockIdx.y * BN;
    const int tid = threadIdx.x;
    const int lane = tid & 63;
    const int wave = tid >> 6;
    const int wm = (wave >> 2) * 64;
    const int wn = (wave & 3) * 64;
    const int fr = lane & 15;
    const int quad = lane >> 4;
    const int sub = lane >> 3;
    const int slot = lane & 7;
    const int jsw = slot ^ sub;
    floatx4 acc[4][4] = {};
    for (int kc = 0; kc < 256; kc += BK) {
#pragma unroll
        for (int p = 0; p < 2; ++p) {
            const int brow = (wave * 2 + p) * 8;
            const int gm = min(m0 + brow + sub, M - 1);
            __builtin_amdgcn_global_load_lds(
                (const AS1 void*)(A + (size_t)gm * 256 + kc + jsw * 8),
                (AS3 void*)(sA + brow * 64), 16, 0, 0);
        }
#pragma unroll
        for (int p = 0; p < 4; ++p) {
            const int brow = (wave * 4 + p) * 8;
            __builtin_amdgcn_global_load_lds(
                (const AS1 void*)(BT + (size_t)(n0 + brow + sub) * 256 + kc + jsw * 8),
                (AS3 void*)(sB + brow * 64), 16, 0, 0);
        }
        __syncthreads();
#pragma unroll
        for (int ks = 0; ks < BK; ks += 32) {
            const int ch = (ks >> 3) + quad;
            const int phys = (ch ^ (fr & 7)) << 3;
            short8 af[4], bfm[4];
#pragma unroll
            for (int i = 0; i < 4; ++i) {
                af[i]  = *reinterpret_cast<const short8*>(&sA[(wm + i * 16 + fr) * 64 + phys]);
                bfm[i] = *reinterpret_cast<const short8*>(&sB[(wn + i * 16 + fr) * 64 + phys]);
            }
#pragma unroll
            for (int mi = 0; mi < 4; ++mi)
#pragma unroll
                for (int ni = 0; ni < 4; ++ni)
                    acc[mi][ni] = __builtin_amdgcn_mfma_f32_16x16x32_bf16(af[mi], bfm[ni], acc[mi][ni], 0, 0, 0);
        }
        __syncthreads();
    }
    float bias4[4];
#pragma unroll
    for (int ni = 0; ni < 4; ++ni) bias4[ni] = bias[n0 + wn + ni * 16 + fr];
    bf16* sC = smem;
    const int myhalf = wn >> 7;
#pragma unroll
    for (int half = 0; half < 2; ++half) {
        if (myhalf == half) {
            const int wnl = wn & 127;
#pragma unroll
            for (int mi = 0; mi < 4; ++mi)
#pragma unroll
                for (int ni = 0; ni < 4; ++ni)
#pragma unroll
                    for (int r = 0; r < 4; ++r)
                        sC[(wm + mi * 16 + quad * 4 + r) * CSTR + wnl + ni * 16 + fr] =
                            f2b(acc[mi][ni][r] + bias4[ni]);
        }
        __syncthreads();
#pragma unroll
        for (int p = 0; p < 4; ++p) {
            int ci = tid + p * 512;
            int row = ci >> 4;
            int c8 = (ci & 15) << 3;
            if (m0 + row < M)
                *reinterpret_cast<uint4*>(C + (size_t)(m0 + row) * Nout + n0 + half * 128 + c8) =
                    *reinterpret_cast<const uint4*>(&sC[row * CSTR + c8]);
        }
        __syncthreads();
    }
}

// ---------------- fused attention: wave-per-node, 2-stage pipelined edge loop (R20) ----------------
__global__ __launch_bounds__(256) void attn_node_kernel(
    const bf16* __restrict__ qkvs,     // [N,1024] q | skip | kv-interleaved
    const float* __restrict__ ecp,     // [32,256] this layer
    const int* __restrict__ indptr, const int2* __restrict__ sorted2,
    const float* __restrict__ Wbeta_l, const float* __restrict__ lng, const float* __restrict__ lnb,
    bf16* __restrict__ hbf, int N) {
    const int tid = threadIdx.x;
    const int wv = tid >> 6;
    const int lane = tid & 63;
    const int n = blockIdx.x * 4 + wv;
    if (n >= N) return;
    const int c0 = lane * 4;
    const ushort4 qu = *reinterpret_cast<const ushort4*>(qkvs + (size_t)n * 1024 + c0);
    const float q0 = us2f(qu.x), q1 = us2f(qu.y), q2 = us2f(qu.z), q3 = us2f(qu.w);
    float a0 = 0.f, a1 = 0.f, a2 = 0.f, a3 = 0.f, wsum = 0.f;
    const int e0 = indptr[n], e1 = indptr[n + 1];
    float4 ep_c;
    uint4 kv_c;
    if (e0 < e1) {
        const int2 sc = sorted2[e0];
        ep_c = *reinterpret_cast<const float4*>(ecp + sc.y * HID + c0);
        kv_c = *reinterpret_cast<const uint4*>(qkvs + (size_t)sc.x * 1024 + 512 + lane * 8);
    }
    for (int ee = e0; ee < e1; ++ee) {
        const float4 ep = ep_c;
        const uint4 kv = kv_c;
        if (ee + 1 < e1) {
            const int2 sc = sorted2[ee + 1];
            ep_c = *reinterpret_cast<const float4*>(ecp + sc.y * HID + c0);
            kv_c = *reinterpret_cast<const uint4*>(qkvs + (size_t)sc.x * 1024 + 512 + lane * 8);
        }
        const float k0 = us2f((unsigned short)(kv.x & 0xffff)), k1 = us2f((unsigned short)(kv.x >> 16));
        const float k2 = us2f((unsigned short)(kv.y & 0xffff)), k3 = us2f((unsigned short)(kv.y >> 16));
        const float v0 = us2f((unsigned short)(kv.z & 0xffff)), v1 = us2f((unsigned short)(kv.z >> 16));
        const float v2 = us2f((unsigned short)(kv.w & 0xffff)), v3 = us2f((unsigned short)(kv.w >> 16));
        float t = q0 * (k0 + ep.x) + q1 * (k1 + ep.y) + q2 * (k2 + ep.z) + q3 * (k3 + ep.w);
        t += __shfl_xor(t, 1); t += __shfl_xor(t, 2); t += __shfl_xor(t, 4); t += __shfl_xor(t, 8);
        const float w = __expf(t * 0.125f);
        a0 += w * (v0 + ep.x);
        a1 += w * (v1 + ep.y);
        a2 += w * (v2 + ep.z);
        a3 += w * (v3 + ep.w);
        wsum += w;
    }
    const float inv = (wsum > 0.f) ? 1.f / wsum : 0.f;
    const float o0 = a0 * inv, o1 = a1 * inv, o2 = a2 * inv, o3 = a3 * inv;
    const ushort4 ru = *reinterpret_cast<const ushort4*>(qkvs + (size_t)n * 1024 + 256 + c0);
    const float r0 = us2f(ru.x), r1 = us2f(ru.y), r2 = us2f(ru.z), r3 = us2f(ru.w);
    const float4 w1 = *reinterpret_cast<const float4*>(Wbeta_l + c0);
    const float4 w2 = *reinterpret_cast<const float4*>(Wbeta_l + 256 + c0);
    const float4 w3 = *reinterpret_cast<const float4*>(Wbeta_l + 512 + c0);
    float tb = o0 * w1.x + o1 * w1.y + o2 * w1.z + o3 * w1.w
             + r0 * w2.x + r1 * w2.y + r2 * w2.z + r3 * w2.w
             + (o0 - r0) * w3.x + (o1 - r1) * w3.y + (o2 - r2) * w3.z + (o3 - r3) * w3.w;
#pragma unroll
    for (int off = 32; off > 0; off >>= 1) tb += __shfl_xor(tb, off);
    const float beta = 1.f / (1.f + __expf(-tb));
    float g0 = fmaxf(beta * r0 + (1.f - beta) * o0, 0.f);
    float g1 = fmaxf(beta * r1 + (1.f - beta) * o1, 0.f);
    float g2 = fmaxf(beta * r2 + (1.f - beta) * o2, 0.f);
    float g3 = fmaxf(beta * r3 + (1.f - beta) * o3, 0.f);
    float s1 = g0 + g1 + g2 + g3;
    float s2 = g0 * g0 + g1 * g1 + g2 * g2 + g3 * g3;
#pragma unroll
    for (int off = 32; off > 0; off >>= 1) { s1 += __shfl_xor(s1, off); s2 += __shfl_xor(s2, off); }
    const float mu = s1 * (1.f / 256.f);
    const float var = s2 * (1.f / 256.f) - mu * mu;
    const float rish = rsqrtf(fmaxf(var, 0.f) + 1e-5f);
    const float4 gg = *reinterpret_cast<const float4*>(lng + c0);
    const float4 bb = *reinterpret_cast<const float4*>(lnb + c0);
    ushort4 hb = *reinterpret_cast<ushort4*>(hbf + (size_t)n * HID + c0);
    float h0 = us2f(hb.x) + (g0 - mu) * rish * gg.x + bb.x;
    float h1 = us2f(hb.y) + (g1 - mu) * rish * gg.y + bb.y;
    float h2 = us2f(hb.z) + (g2 - mu) * rish * gg.z + bb.z;
    float h3 = us2f(hb.w) + (g3 - mu) * rish * gg.w + bb.w;
    hb.x = f2us(h0); hb.y = f2us(h1); hb.z = f2us(h2); hb.w = f2us(h3);
    *reinterpret_cast<ushort4*>(hbf + (size_t)n * HID + c0) = hb;
}

// ---------------- hierarchical pooling (reads bf16 h) ----------------
__global__ __launch_bounds__(256) void pool_kernel(const bf16* __restrict__ hbf,
                                                   const int* __restrict__ batch,
                                                   float* __restrict__ pooled, int N) {
    __shared__ int sb[64];
    const int c = threadIdx.x;
    const int n0 = blockIdx.x * 64;
    const int cnt = min(64, N - n0);
    if (c < 64 && c < cnt) sb[c] = batch[n0 + c];
    __syncthreads();
    float acc = 0.f;
    int gcur = sb[0];
    for (int i = 0; i < cnt; ++i) {
        const int g = sb[i];
        if (g != gcur) {
            atomicAdd(&pooled[(size_t)gcur * HID + c], acc);
            acc = 0.f;
            gcur = g;
        }
        acc += b2f(hbf[(size_t)(n0 + i) * HID + c]);
    }
    atomicAdd(&pooled[(size_t)gcur * HID + c], acc);
}

__global__ void pragma_kernel(const float* __restrict__ scalars,
                              const float* __restrict__ pw1, const float* __restrict__ pb1,
                              const float* __restrict__ pw2, const float* __restrict__ pb2,
                              float* __restrict__ pooled) {
    int g = blockIdx.x, c = threadIdx.x;
    __shared__ float s5[5];
    __shared__ float t1[256];
    if (c < 5) s5[c] = scalars[g * 5 + c];
    __syncthreads();
    float a = pb1[c];
    for (int k = 0; k < 5; ++k) a += s5[k] * pw1[k * 256 + c];
    t1[c] = fmaxf(a, 0.f);
    __syncthreads();
    float p = pb2[c];
    for (int j = 0; j < 256; ++j) p += t1[j] * pw2[j * 256 + c];
    pooled[g * 256 + c] += p;
}

__global__ void readout_kernel(const float* __restrict__ pooled,
                               const float* __restrict__ rw1, const float* __restrict__ rb1,
                               const float* __restrict__ rw2, const float* __restrict__ rb2,
                               const float* __restrict__ rw3, const float* __restrict__ rb3,
                               float* __restrict__ out) {
    int g = blockIdx.x, c = threadIdx.x;
    __shared__ float pl[256], z1[256], z2[128];
    pl[c] = pooled[g * 256 + c];
    __syncthreads();
    float z = rb1[c];
    for (int k = 0; k < 256; ++k) z += pl[k] * rw1[k * 256 + c];
    z1[c] = fmaxf(z, 0.f);
    __syncthreads();
    if (c < 128) {
        float v = rb2[c];
        for (int j = 0; j < 256; ++j) v += z1[j] * rw2[j * 128 + c];
        z2[c] = fmaxf(v, 0.f);
    }
    __syncthreads();
    if (c < 4) {
        float o = rb3[c];
        for (int j = 0; j < 128; ++j) o += z2[j] * rw3[j * 4 + c];
        out[g * 4 + c] = o;
    }
}

extern "C" void kernel_launch(void* const* d_in, const int* in_sizes, int n_in,
                              void* d_out, int out_size, void* d_ws, size_t ws_size,
                              hipStream_t stream) {
    const int* x          = (const int*)d_in[0];
    const int* edge_attr  = (const int*)d_in[1];
    const int* edge_index = (const int*)d_in[2];
    const int* batch      = (const int*)d_in[3];
    const float* scalars  = (const float*)d_in[4];
    const float* ne0 = (const float*)d_in[6];
    const float* ne1 = (const float*)d_in[7];
    const float* ne2 = (const float*)d_in[8];
    const float* ee0 = (const float*)d_in[9];
    const float* ee1 = (const float*)d_in[10];
    const float* Wq = (const float*)d_in[11];
    const float* bq = (const float*)d_in[12];
    const float* Wk = (const float*)d_in[13];
    const float* bk = (const float*)d_in[14];
    const float* Wv = (const float*)d_in[15];
    const float* bv = (const float*)d_in[16];
    const float* We = (const float*)d_in[17];
    const float* be = (const float*)d_in[18];
    const float* Wskip = (const float*)d_in[19];
    const float* bskip = (const float*)d_in[20];
    const float* Wbeta = (const float*)d_in[21];
    const float* ln_g = (const float*)d_in[22];
    const float* ln_b = (const float*)d_in[23];
    const float* pw1 = (const float*)d_in[24];
    const float* pb1 = (const float*)d_in[25];
    const float* pw2 = (const float*)d_in[26];
    const float* pb2 = (const float*)d_in[27];
    const float* rw1 = (const float*)d_in[28];
    const float* rb1 = (const float*)d_in[29];
    const float* rw2 = (const float*)d_in[30];
    const float* rb2 = (const float*)d_in[31];
    const float* rw3 = (const float*)d_in[32];
    const float* rb3 = (const float*)d_in[33];

    const int N = in_sizes[0] / 3;
    const int E = in_sizes[1] / 2;
    const int G = in_sizes[4] / 5;

    char* base = (char*)d_ws;
    size_t off = 0;
    auto carve = [&](size_t bytes) -> char* {
        char* p = base + off;
        off += (bytes + 255) & ~(size_t)255;
        return p;
    };
    bf16*  hbf    = (bf16*)carve((size_t)N * HID * 2);
    bf16*  qkvs   = (bf16*)carve((size_t)N * 1024 * 2);
    float* ec     = (float*)carve((size_t)32 * HID * 4);
    float* ecp4   = (float*)carve((size_t)NL * 32 * HID * 4);
    int*   ecid   = (int*)carve((size_t)E * 4);
    float* pooled = (float*)carve((size_t)G * HID * 4);
    bf16*  wcatT  = (bf16*)carve((size_t)NL * 1024 * 256 * 2);
    float* bcat   = (float*)carve((size_t)NL * 1024 * 4);
    int* counts   = (int*)carve((size_t)N * 4);
    int* fill     = (int*)carve((size_t)N * 4);
    int* incl     = (int*)carve((size_t)N * 4);
    int* bsum     = (int*)carve(4096);
    int* boff     = (int*)carve(4096);
    int* indptr   = (int*)carve((size_t)(N + 1) * 4);
    int2* sorted2 = (int2*)carve((size_t)E * 8);
    // total ~140 MB

    const int* srcv = edge_index;
    const int* dstv = edge_index + E;

    zero_ws_kernel<<<(N + 255) / 256, 256, 0, stream>>>(counts, fill, N, pooled, G * HID);
    node_embed_kernel<<<N, 256, 0, stream>>>(x, ne0, ne1, ne2, hbf);
    ecombo_embed_kernel<<<32, 256, 0, stream>>>(ee0, ee1, ec);
    edge_prep_kernel<<<(E + 255) / 256, 256, 0, stream>>>(edge_attr, dstv, E, ecid, counts);
    pack_wcat_kernel<<<4096, 256, 0, stream>>>(Wq, Wk, Wv, Wskip, wcatT);
    pack_bias_kernel<<<16, 256, 0, stream>>>(bq, bk, bv, bskip, bcat);
    combo_proj_kernel<<<NL * 32, 256, 0, stream>>>(ec, We, be, ecp4);

    int nsb = (N + 255) / 256;
    scan_local_kernel<<<nsb, 256, 0, stream>>>(counts, N, incl, bsum);
    scan_block_kernel<<<1, 256, 0, stream>>>(bsum, nsb, boff);
    scan_add_kernel<<<nsb, 256, 0, stream>>>(incl, boff, N, indptr);
    fill_sorted_kernel<<<(E + 255) / 256, 256, 0, stream>>>(dstv, srcv, ecid, indptr, E, fill, sorted2);

    for (int l = 0; l < NL; ++l) {
        dim3 g1((N + 127) / 128, 4);
        gemm_bt_kernel<<<g1, 512, 0, stream>>>(hbf, wcatT + (size_t)l * 1024 * 256,
                                               bcat + (size_t)l * 1024, qkvs, N, 1024);
        attn_node_kernel<<<(N + 3) / 4, 256, 0, stream>>>(qkvs, ecp4 + (size_t)l * 32 * HID,
                                                          indptr, sorted2,
                                                          Wbeta + (size_t)l * 768,
                                                          ln_g + (size_t)l * 256, ln_b + (size_t)l * 256,
                                                          hbf, N);
    }

    pool_kernel<<<(N + 63) / 64, 256, 0, stream>>>(hbf, batch, pooled, N);
    pragma_kernel<<<G, 256, 0, stream>>>(scalars, pw1, pb1, pw2, pb2, pooled);
    readout_kernel<<<G, 256, 0, stream>>>(pooled, rw1, rb1, rw2, rb2, rw3, rb3, (float*)d_out);
}